// Round 1
// baseline (6097.755 us; speedup 1.0000x reference)
//
#include <hip/hip_runtime.h>

#define B_ 128
#define T_ 2048
#define D_ 128
#define H_ 512
#define L_ 10
#define NG 8      // batch groups
#define GB 16     // batches per group (MFMA N)
#define NS 16     // gate-slice workgroups per group
#define HS 32     // hidden units per slice
#define NKK 20    // K-steps of 32 (16 h-steps + 4 x-steps)

typedef __attribute__((ext_vector_type(8))) short short8;
typedef __attribute__((ext_vector_type(4))) float f32x4;
typedef unsigned long long u64;

__device__ __forceinline__ unsigned short f2bf(float f) {
    union { float f; unsigned u; } v; v.f = f;
    unsigned r = v.u + 0x7fffu + ((v.u >> 16) & 1u);
    return (unsigned short)(r >> 16);
}
__device__ __forceinline__ float fast_sig(float x) {
    return 1.f / (1.f + __expf(-x));
}
__device__ __forceinline__ float fast_tanh(float x) {
    // 1 - 2/(e^{2x}+1); exp overflow -> inf -> 1-0 = 1 (correct saturation)
    return 1.f - 2.f / (__expf(2.f * x) + 1.f);
}

// Persistent LSTM. Grid = 128 = 8 groups x 16 slices. Weights in VGPRs as
// MFMA A-fragments, GATE-INTERLEAVED: tile row m covers (gate = m&3,
// hu = s*32 + w*4 + (m>>2)), so after MFMA each lane holds all 4 gates of
// one (hu, batch) in acc[0..3] -> elementwise is fully lane-local (no
// gate_lds, one fewer barrier per step). Cross-WG h exchange via RELAXED
// agent-scope u64 atomics; per-slice monotone flags replace the fetch_add
// arrival counter (no RMW serialization at the coherence point).
__global__ __launch_bounds__(512, 2) void lstm_kernel(
    const float* __restrict__ x, const float* __restrict__ W_ih,
    const float* __restrict__ W_hh, const float* __restrict__ bias,
    u64* h_buf,               // [2][16384] u64 = [2][128][512] bf16
    unsigned int* flags,      // [8][16] monotone step counters
    float* __restrict__ hfin) // [128][512] fp32
{
    const int g    = blockIdx.x & 7;
    const int s    = blockIdx.x >> 3;
    const int tid  = threadIdx.x;
    const int lane = tid & 63;
    const int w    = tid >> 6;     // wave 0..7
    const int quad = lane >> 4;    // 0..3
    const int col  = lane & 15;    // MFMA N index (batch within group)

    __shared__ short Bstage[NKK * 64 * 8];          // 20480 B, fragment-order

    // ---- one-time: gate-interleaved weight A-fragments (bf16) ----
    // tile row m -> weight row (m&3)*512 + s*32 + w*4 + (m>>2); K=[h(512)|x(128)]
    short8 wfrag[NKK];
    {
        const int m = col;
        const int r = (m & 3) * 512 + s * HS + w * 4 + (m >> 2);
        #pragma unroll
        for (int kk = 0; kk < NKK; ++kk) {
            const int k0 = kk * 32 + quad * 8;
            short8 v;
            #pragma unroll
            for (int j = 0; j < 8; ++j) {
                const int k = k0 + j;
                const float f = (k < 512) ? W_hh[r * 512 + k]
                                          : W_ih[r * 128 + (k - 512)];
                v[j] = (short)f2bf(f);
            }
            wfrag[kk] = v;
        }
    }

    // ---- per-lane output element: C/D row quad*4+rr -> (hu=.., gate=rr) ----
    const int hu_g = s * HS + w * 4 + quad;
    const int bb   = g * GB + col;
    const float bi  = bias[0 * 512 + hu_g];
    const float bfv = bias[1 * 512 + hu_g];
    const float bg  = bias[2 * 512 + hu_g];
    const float bo  = bias[3 * 512 + hu_g];
    float c_val = 0.f;

    // x staging addresses (waves 0..3 only)
    const float* xbase = nullptr;
    int xc = 0;
    if (tid < 256) {
        const int kk = tid >> 6;              // 0..3
        const int ln = tid & 63;
        const int n  = ln & 15;
        const int k0 = kk * 32 + (ln >> 4) * 8;
        xbase = x + (size_t)(g * GB + n) * T_ * D_ + k0;
        xc = (16 + kk) * 64 + ln;
    }

    // h staging addresses: 2 chunks/thread, u64-wide
    u64* hp0; u64* hp1; int hc0, hc1;
    {
        int c  = tid;
        int kk = c >> 6, ln = c & 63;
        hp0 = h_buf + ((size_t)(g * GB + (ln & 15)) * H_ + kk * 32 + (ln >> 4) * 8) / 4;
        hc0 = c;
        c  = tid + 512;
        kk = c >> 6; ln = c & 63;
        hp1 = h_buf + ((size_t)(g * GB + (ln & 15)) * H_ + kk * 32 + (ln >> 4) * 8) / 4;
        hc1 = c;
    }
    u64* hdst = h_buf + (size_t)bb * 128 + s * 8 + w;
    const unsigned int* fpoll = flags + g * 16 + col;

    for (int t = 0; t < T_; ++t) {
        // ---- issue x loads early: HBM latency hides under the poll ----
        float4 xa = {0,0,0,0}, xb = {0,0,0,0};
        if (tid < 256) {
            const float4* p = (const float4*)(xbase + (size_t)t * D_);
            xa = p[0]; xb = p[1];
        }

        // ---- poll per-slice flags (one coalesced 64B line per wave) ----
        if (t > 0) {
            while (__hip_atomic_load(fpoll, __ATOMIC_RELAXED,
                                     __HIP_MEMORY_SCOPE_AGENT) < (unsigned)t) {}
        }
        __asm__ __volatile__("" ::: "memory");

        // ---- stage x fragments ----
        if (tid < 256) {
            short8 v;
            v[0] = (short)f2bf(xa.x); v[1] = (short)f2bf(xa.y);
            v[2] = (short)f2bf(xa.z); v[3] = (short)f2bf(xa.w);
            v[4] = (short)f2bf(xb.x); v[5] = (short)f2bf(xb.y);
            v[6] = (short)f2bf(xb.z); v[7] = (short)f2bf(xb.w);
            *(short8*)&Bstage[xc * 8] = v;
        }

        // ---- stage h fragments via relaxed agent u64 loads ----
        {
            const size_t boff = (size_t)(t & 1) * 16384;
            union { u64 q[2]; short8 v; } r0, r1;
            u64* sp0 = hp0 + boff;
            u64* sp1 = hp1 + boff;
            r0.q[0] = __hip_atomic_load(sp0 + 0, __ATOMIC_RELAXED, __HIP_MEMORY_SCOPE_AGENT);
            r0.q[1] = __hip_atomic_load(sp0 + 1, __ATOMIC_RELAXED, __HIP_MEMORY_SCOPE_AGENT);
            r1.q[0] = __hip_atomic_load(sp1 + 0, __ATOMIC_RELAXED, __HIP_MEMORY_SCOPE_AGENT);
            r1.q[1] = __hip_atomic_load(sp1 + 1, __ATOMIC_RELAXED, __HIP_MEMORY_SCOPE_AGENT);
            *(short8*)&Bstage[hc0 * 8] = r0.v;
            *(short8*)&Bstage[hc1 * 8] = r1.v;
        }
        __syncthreads();

        // ---- MFMA, K=640, two independent accumulator chains ----
        f32x4 acc0 = {0.f, 0.f, 0.f, 0.f}, acc1 = {0.f, 0.f, 0.f, 0.f};
        #pragma unroll
        for (int kk = 0; kk < NKK; kk += 2) {
            const short8 b0 = *(const short8*)&Bstage[(kk * 64 + lane) * 8];
            const short8 b1 = *(const short8*)&Bstage[((kk + 1) * 64 + lane) * 8];
            acc0 = __builtin_amdgcn_mfma_f32_16x16x32_bf16(wfrag[kk], b0, acc0, 0, 0, 0);
            acc1 = __builtin_amdgcn_mfma_f32_16x16x32_bf16(wfrag[kk + 1], b1, acc1, 0, 0, 0);
        }

        // ---- elementwise cell: fully lane-local (acc[rr] = gate rr) ----
        {
            const float gi = acc0[0] + acc1[0] + bi;
            const float gf = acc0[1] + acc1[1] + bfv;
            const float gg = acc0[2] + acc1[2] + bg;
            const float go = acc0[3] + acc1[3] + bo;
            c_val = fast_sig(gf) * c_val + fast_sig(gi) * fast_tanh(gg);
            const float h = fast_sig(go) * fast_tanh(c_val);
            // gather 4 adjacent hu (quads 0..3, same batch col) into one u64
            const float h1 = __shfl_down(h, 16, 64);
            const float h2 = __shfl_down(h, 32, 64);
            const float h3 = __shfl_down(h, 48, 64);
            if (quad == 0) {
                const u64 val = (u64)f2bf(h)         | ((u64)f2bf(h1) << 16)
                              | ((u64)f2bf(h2) << 32) | ((u64)f2bf(h3) << 48);
                __hip_atomic_store(hdst + (size_t)((t + 1) & 1) * 16384, val,
                                   __ATOMIC_RELAXED, __HIP_MEMORY_SCOPE_AGENT);
            }
            if (t == T_ - 1) hfin[(size_t)bb * H_ + hu_g] = h;
        }
        __syncthreads();   // drains vmcnt(0): h stores at coherence point

        // ---- publish: plain relaxed store of monotone step counter ----
        if (tid == 0)
            __hip_atomic_store(&flags[g * 16 + s], (unsigned)(t + 1),
                               __ATOMIC_RELAXED, __HIP_MEMORY_SCOPE_AGENT);
    }
}

// Head: logits = h_final @ W_out^T, softmax. One wave per batch row.
__global__ void head_kernel(const float* __restrict__ hfin,
                            const float* __restrict__ W_out,
                            float* __restrict__ out)
{
    const int bidx = blockIdx.x;
    const int l    = threadIdx.x;      // 0..63
    float hv[8];
    #pragma unroll
    for (int j = 0; j < 8; ++j) hv[j] = hfin[bidx * 512 + j * 64 + l];
    __shared__ float logits[L_];
    for (int o = 0; o < L_; ++o) {
        float p = 0.f;
        #pragma unroll
        for (int j = 0; j < 8; ++j) p += hv[j] * W_out[o * 512 + j * 64 + l];
        #pragma unroll
        for (int off = 32; off; off >>= 1) p += __shfl_down(p, off, 64);
        if (l == 0) logits[o] = p;
    }
    __syncthreads();
    if (l == 0) {
        float mx = logits[0];
        for (int o = 1; o < L_; ++o) mx = fmaxf(mx, logits[o]);
        float e[L_], sum = 0.f;
        for (int o = 0; o < L_; ++o) { e[o] = __expf(logits[o] - mx); sum += e[o]; }
        const float inv = 1.f / sum;
        for (int o = 0; o < L_; ++o) out[bidx * L_ + o] = e[o] * inv;
    }
}

extern "C" void kernel_launch(void* const* d_in, const int* in_sizes, int n_in,
                              void* d_out, int out_size, void* d_ws, size_t ws_size,
                              hipStream_t stream) {
    const float* x     = (const float*)d_in[0];
    const float* W_ih  = (const float*)d_in[1];
    const float* W_hh  = (const float*)d_in[2];
    const float* bias  = (const float*)d_in[3];
    const float* W_out = (const float*)d_in[4];
    float* out = (float*)d_out;

    // ws: h_buf [2][128][512] bf16 (262144 B) | flags [8][16] u32 (512 B,
    // padded to 1024) | hfin [128][512] f32 (262144 B)
    char* ws = (char*)d_ws;
    u64*          h_buf = (u64*)ws;
    unsigned int* flags = (unsigned int*)(ws + 262144);
    float*        hfin  = (float*)(ws + 262144 + 1024);

    hipMemsetAsync(ws, 0, 262144 + 1024, stream);

    void* args[] = { (void*)&x, (void*)&W_ih, (void*)&W_hh, (void*)&bias,
                     (void*)&h_buf, (void*)&flags, (void*)&hfin };
    hipLaunchCooperativeKernel((void*)lstm_kernel, dim3(NG * NS), dim3(512),
                               args, 0, stream);
    head_kernel<<<dim3(B_), dim3(64), 0, stream>>>(hfin, W_out, out);
}